// Round 7
// baseline (117.553 us; speedup 1.0000x reference)
//
#include <hip/hip_runtime.h>

// GNN_51539607552576 — round 7.
// Phase 1 (proj): async DMA staging. global_load_lds (width 16) stages 32-ch x
//   256-px fp32 tiles into double-buffered LDS; counted s_waitcnt vmcnt(8) +
//   raw s_barrier keep 8-16 KB/wave in flight at ZERO VGPR cost. Thread t owns
//   pixel t: scalar ds_read (conflict-free), 28 FMAs/ch, no LDS reduce.
// Phase 2 (gnn_node): unchanged (per-output-node split, ~10 us).

namespace {
constexpr int S     = 128 * 128;
constexpr int BATCH = 4;
constexpr int HID   = 10;
constexpr int INDIM = 256;
constexpr int NPIX  = BATCH * S;   // 65536

constexpr int PX   = 256;          // pixels per block (= blockDim.x)
constexpr int TC   = 32;           // channels per tile
constexpr int NT   = INDIM / TC;   // 8 tiles
constexpr int TILE = TC * PX;      // floats per LDS buffer (32 KB)

struct Ptrs {
  const float* __restrict__ xp;
  const float* __restrict__ xh;
  const float* __restrict__ xf;
  const float* __restrict__ p_fea;
  const float* __restrict__ h_fea;
  const float* __restrict__ Wf_comp;  const float* __restrict__ bf_comp;
  const float* __restrict__ Wf_uatt;  const float* __restrict__ bf_uatt;
  const float* __restrict__ Wf_uupd;
  const float* __restrict__ Wh_pdp_f; const float* __restrict__ Wh_pdp_x;
  const float* __restrict__ bh_pdp;
  const float* __restrict__ Wh_att;   const float* __restrict__ bh_att;
  const float* __restrict__ Wh_cu;    const float* __restrict__ bh_cu;
  const float* __restrict__ Wh_cl;    const float* __restrict__ bh_cl;
  const float* __restrict__ Wh_dec_f; const float* __restrict__ Wh_dec_x;
  const float* __restrict__ bh_dec;
  const float* __restrict__ Wh_uatt;  const float* __restrict__ bh_uatt;
  const float* __restrict__ Wh_uupd;
  const float* __restrict__ Wp_pdp_f; const float* __restrict__ Wp_pdp_x;
  const float* __restrict__ bp_pdp;
  const float* __restrict__ Wp_att;   const float* __restrict__ bp_att;
  const float* __restrict__ Wp_dec_f; const float* __restrict__ Wp_dec_x;
  const float* __restrict__ bp_dec;
  const float* __restrict__ Wp_uatt;  const float* __restrict__ bp_uatt;
  const float* __restrict__ Wp_uupd;
  float* __restrict__ out;
  float* __restrict__ ws;
};

__device__ __forceinline__ float sigmoidf(float x) {
  return 1.0f / (1.0f + __expf(-x));
}

// ============================ Phase 1: projections ============================
// ws rows: 0..9 fh, 10..11 hdec, 12..21 fpj, 22..27 pdec. Column = pixel id.
// Each wave DMAs 8 channel-rows (1 KB each) per tile: vmcnt += 8 per STAGE.

template <int NO>  // 12 (h stream) or 16 (p stream)
__device__ __forceinline__ void proj_impl(
    float* lds,                           // [2][TILE]
    const float* __restrict__ fea,
    const float* __restrict__ Wa,         // [10][INDIM]
    const float* __restrict__ Wb,         // [NO-10][INDIM]
    float* __restrict__ ws, int obase) {
  const int t    = threadIdx.x;
  const int lane = t & 63;
  const int wid  = __builtin_amdgcn_readfirstlane(t >> 6);
  const int pb   = blockIdx.x * PX;
  const int b    = pb >> 14;
  const int p0   = pb & (S - 1);
  const float* __restrict__ fb = fea + (size_t)b * INDIM * S + p0;

  // stage one 32-channel tile into buf via async DMA (8 rows per wave)
  auto STAGE = [&](int tile) {
    float* dst = lds + (tile & 1) * TILE;
    const int cb = tile * TC;
#pragma unroll
    for (int j = 0; j < TC / 4; ++j) {          // 8 channels per wave
      const int cl = wid * (TC / 4) + j;        // local channel 0..31
      const float* g = fb + (size_t)(cb + cl) * S + lane * 4;  // 16 B/lane
      __builtin_amdgcn_global_load_lds(
          (const __attribute__((address_space(1))) void*)g,
          (__attribute__((address_space(3))) void*)(dst + cl * PX),
          16, 0, 0);
    }
  };

  float acc[NO];
#pragma unroll
  for (int o = 0; o < NO; ++o) acc[o] = 0.f;

  STAGE(0);

#pragma unroll 1
  for (int tile = 0; tile < NT; ++tile) {
    if (tile + 1 < NT) {
      STAGE(tile + 1);
      // wait only for THIS tile's 8 rows; next tile's 8 stay in flight
      asm volatile("s_waitcnt vmcnt(8)" ::: "memory");
    } else {
      asm volatile("s_waitcnt vmcnt(0)" ::: "memory");
    }
    __builtin_amdgcn_s_barrier();   // all waves' rows for this tile landed

    const float* buf = lds + (tile & 1) * TILE;
    const int cb = tile * TC;
#pragma unroll
    for (int c = 0; c < TC; ++c) {
      const float v = buf[c * PX + t];          // lane-consecutive: conflict-free
      const int ch = __builtin_amdgcn_readfirstlane(cb + c);  // force s_load weights
#pragma unroll
      for (int o = 0; o < 10; ++o)
        acc[o] = fmaf(v, Wa[o * INDIM + ch], acc[o]);
#pragma unroll
      for (int o = 10; o < NO; ++o)
        acc[o] = fmaf(v, Wb[(o - 10) * INDIM + ch], acc[o]);
    }
    // our LDS reads are in registers before we let anyone overwrite this buf
    asm volatile("s_waitcnt lgkmcnt(0)" ::: "memory");
    __builtin_amdgcn_s_barrier();
  }

#pragma unroll
  for (int o = 0; o < NO; ++o)
    ws[(size_t)(obase + o) * NPIX + pb + t] = acc[o];
}

__global__ __launch_bounds__(256) void proj_kernel(Ptrs P) {
  __shared__ float lds[2 * TILE];   // 64 KB -> 2 blocks/CU
  if (blockIdx.y == 0) {
    proj_impl<12>(lds, P.h_fea, P.Wh_pdp_f, P.Wh_dec_f, P.ws, 0);
  } else {
    proj_impl<16>(lds, P.p_fea, P.Wp_pdp_f, P.Wp_dec_f, P.ws, 12);
  }
}

// ============================ Phase 2: per-node graph math ============================

__device__ __forceinline__ void att_update_store(
    const float* x, const float* m,
    const float* __restrict__ Wa, float ba, const float* __restrict__ Wu,
    float* __restrict__ outp) {
  float a = ba;
#pragma unroll
  for (int c = 0; c < HID; ++c) a = fmaf(x[c], Wa[c], a);
#pragma unroll
  for (int c = 0; c < HID; ++c) a = fmaf(m[c], Wa[HID + c], a);
  a = sigmoidf(a);
#pragma unroll
  for (int o = 0; o < HID; ++o) {
    float u = 0.f;
#pragma unroll
    for (int c = 0; c < HID; ++c) u = fmaf(x[c], Wu[o * 2 * HID + c], u);
#pragma unroll
    for (int c = 0; c < HID; ++c) u = fmaf(m[c], Wu[o * 2 * HID + HID + c], u);
    u = fmaxf(u, 0.f);
    outp[(size_t)o * S] = x[o] * (1.f - a) + u * a;
  }
}

__device__ __forceinline__ void load10(float* dst, const float* __restrict__ src,
                                       int plane, int p) {
#pragma unroll
  for (int c = 0; c < HID; ++c)
    dst[c] = src[((size_t)plane * HID + c) * S + p];
}

// grid.y = node id: 0..5 parts, 6..7 halves, 8 full
__global__ __launch_bounds__(256) void gnn_node(Ptrs P) {
  const int tid = blockIdx.x * blockDim.x + threadIdx.x;
  const int b = tid >> 14;
  const int p = tid & (S - 1);
  const int y = blockIdx.y;

  if (y == 8) {
    // ---------------- full graph ----------------
    float xh0[HID], xh1[HID], xfv[HID];
    load10(xh0, P.xh, 0 * BATCH + b, p);
    load10(xh1, P.xh, 1 * BATCH + b, p);
    load10(xfv, P.xf, b, p);
    float a0 = P.bf_comp[0], a1 = P.bf_comp[1];
#pragma unroll
    for (int c = 0; c < HID; ++c) {
      a0 = fmaf(xh0[c], P.Wf_comp[c], a0);
      a1 = fmaf(xh1[c], P.Wf_comp[HID + c], a1);
    }
    a0 = sigmoidf(a0); a1 = sigmoidf(a1);
    float msg[HID];
#pragma unroll
    for (int c = 0; c < HID; ++c) msg[c] = a0 * xh0[c] + a1 * xh1[c];
    att_update_store(xfv, msg, P.Wf_uatt, P.bf_uatt[0], P.Wf_uupd,
                     P.out + ((size_t)(8 * BATCH + b) * HID) * S + p);
  } else if (y >= 6) {
    // ---------------- half graph, node h ----------------
    const int h = y - 6;
    float xh_self[HID], xh_oth[HID], xfv[HID], fh[HID];
    load10(xh_self, P.xh, h * BATCH + b, p);
    load10(xh_oth,  P.xh, (1 - h) * BATCH + b, p);
    load10(xfv, P.xf, b, p);
#pragma unroll
    for (int o = 0; o < HID; ++o) fh[o] = P.ws[(size_t)o * NPIX + tid];
    const float hdec = P.ws[(size_t)(10 + h) * NPIX + tid];

    const int nsrc = h ? 2 : 4;
    const int sbase = h ? 4 : 0;
    const float* __restrict__ Wc = h ? P.Wh_cl : P.Wh_cu;
    const float* __restrict__ bc = h ? P.bh_cl : P.bh_cu;
    float comp[HID];
#pragma unroll
    for (int o = 0; o < HID; ++o) comp[o] = 0.f;
#pragma unroll
    for (int i = 0; i < 4; ++i) {
      if (i < nsrc) {
        float xpi[HID];
        load10(xpi, P.xp, (sbase + i) * BATCH + b, p);
        float s = bc[i];
#pragma unroll
        for (int c = 0; c < HID; ++c) s = fmaf(xpi[c], Wc[i * HID + c], s);
        s = sigmoidf(s);
#pragma unroll
        for (int c = 0; c < HID; ++c) comp[c] = fmaf(s, xpi[c], comp[c]);
      }
    }

    float a_self = P.bh_att[h], a_oth = P.bh_att[1 - h];
#pragma unroll
    for (int c = 0; c < HID; ++c) {
      a_self = fmaf(xh_self[c], P.Wh_att[h * HID + c], a_self);
      a_oth  = fmaf(xh_oth[c],  P.Wh_att[(1 - h) * HID + c], a_oth);
    }
    a_self = sigmoidf(a_self); a_oth = sigmoidf(a_oth);
    const float wg = a_oth * (1.f - a_self);

    float d = hdec + P.bh_dec[h];
#pragma unroll
    for (int c = 0; c < HID; ++c) d = fmaf(xh_self[c], P.Wh_dec_x[h * HID + c], d);
    d = sigmoidf(d);

    float m[HID];
#pragma unroll
    for (int o = 0; o < HID; ++o) {
      float dp = fh[o] + P.bh_pdp[o];
#pragma unroll
      for (int c = 0; c < HID; ++c) dp = fmaf(xh_oth[c], P.Wh_pdp_x[o * HID + c], dp);
      dp = fmaxf(dp, 0.f);
      m[o] = comp[o] + dp * wg + d * xfv[o];
    }
    att_update_store(xh_self, m, P.Wh_uatt + h * 2 * HID, P.bh_uatt[h],
                     P.Wh_uupd + h * HID * 2 * HID,
                     P.out + ((size_t)((6 + h) * BATCH + b) * HID) * S + p);
  } else {
    // ---------------- part graph, node n ----------------
    const int n = y;
    const int half = (n < 4) ? 0 : 1;
    // ADJ columns: dst0{1} dst1{0,2,3,4,5} dst2{1} dst3{1} dst4{1,5} dst5{1,4}
    const unsigned masks[6] = {0x02u, 0x3Du, 0x02u, 0x02u, 0x22u, 0x12u};
    const unsigned mask = masks[n];

    float xpn[HID], xh_s[HID], fpj[HID];
    load10(xpn, P.xp, n * BATCH + b, p);
    load10(xh_s, P.xh, half * BATCH + b, p);
#pragma unroll
    for (int o = 0; o < HID; ++o) fpj[o] = P.ws[(size_t)(12 + o) * NPIX + tid];
    const float pdecn = P.ws[(size_t)(22 + n) * NPIX + tid];

    float pattn = P.bp_att[n];
#pragma unroll
    for (int c = 0; c < HID; ++c) pattn = fmaf(xpn[c], P.Wp_att[n * HID + c], pattn);
    pattn = sigmoidf(pattn);

    float msum[HID];
#pragma unroll
    for (int o = 0; o < HID; ++o) msum[o] = 0.f;
#pragma unroll
    for (int src = 0; src < 6; ++src) {
      if (mask & (1u << src)) {
        float xps[HID];
        load10(xps, P.xp, src * BATCH + b, p);
        float ps = P.bp_att[src];
#pragma unroll
        for (int c = 0; c < HID; ++c) ps = fmaf(xps[c], P.Wp_att[src * HID + c], ps);
        ps = sigmoidf(ps);
#pragma unroll
        for (int o = 0; o < HID; ++o) {
          float dp = fpj[o] + P.bp_pdp[o];
#pragma unroll
          for (int c = 0; c < HID; ++c) dp = fmaf(xps[c], P.Wp_pdp_x[o * HID + c], dp);
          msum[o] = fmaf(fmaxf(dp, 0.f), ps, msum[o]);
        }
      }
    }

    float dg = pdecn + P.bp_dec[n];
#pragma unroll
    for (int c = 0; c < HID; ++c) dg = fmaf(xpn[c], P.Wp_dec_x[n * HID + c], dg);
    dg = sigmoidf(dg);

    const float onem = 1.f - pattn;
    float m[HID];
#pragma unroll
    for (int o = 0; o < HID; ++o) m[o] = onem * msum[o] + dg * xh_s[o];

    att_update_store(xpn, m, P.Wp_uatt + n * 2 * HID, P.bp_uatt[n],
                     P.Wp_uupd + n * HID * 2 * HID,
                     P.out + ((size_t)(n * BATCH + b) * HID) * S + p);
  }
}

}  // namespace

extern "C" void kernel_launch(void* const* d_in, const int* in_sizes, int n_in,
                              void* d_out, int out_size, void* d_ws, size_t ws_size,
                              hipStream_t stream) {
  Ptrs P;
  P.xp       = (const float*)d_in[0];
  P.xh       = (const float*)d_in[1];
  P.xf       = (const float*)d_in[2];
  // d_in[3] = bg_node (unused)
  P.p_fea    = (const float*)d_in[4];
  P.h_fea    = (const float*)d_in[5];
  // d_in[6] = f_fea (unused)
  P.Wf_comp  = (const float*)d_in[7];
  P.bf_comp  = (const float*)d_in[8];
  P.Wf_uatt  = (const float*)d_in[9];
  P.bf_uatt  = (const float*)d_in[10];
  P.Wf_uupd  = (const float*)d_in[11];
  P.Wh_pdp_f = (const float*)d_in[12];
  P.Wh_pdp_x = (const float*)d_in[13];
  P.bh_pdp   = (const float*)d_in[14];
  P.Wh_att   = (const float*)d_in[15];
  P.bh_att   = (const float*)d_in[16];
  P.Wh_cu    = (const float*)d_in[17];
  P.bh_cu    = (const float*)d_in[18];
  P.Wh_cl    = (const float*)d_in[19];
  P.bh_cl    = (const float*)d_in[20];
  P.Wh_dec_f = (const float*)d_in[21];
  P.Wh_dec_x = (const float*)d_in[22];
  P.bh_dec   = (const float*)d_in[23];
  P.Wh_uatt  = (const float*)d_in[24];
  P.bh_uatt  = (const float*)d_in[25];
  P.Wh_uupd  = (const float*)d_in[26];
  P.Wp_pdp_f = (const float*)d_in[27];
  P.Wp_pdp_x = (const float*)d_in[28];
  P.bp_pdp   = (const float*)d_in[29];
  P.Wp_att   = (const float*)d_in[30];
  P.bp_att   = (const float*)d_in[31];
  P.Wp_dec_f = (const float*)d_in[32];
  P.Wp_dec_x = (const float*)d_in[33];
  P.bp_dec   = (const float*)d_in[34];
  P.Wp_uatt  = (const float*)d_in[35];
  P.bp_uatt  = (const float*)d_in[36];
  P.Wp_uupd  = (const float*)d_in[37];
  P.out      = (float*)d_out;
  P.ws       = (float*)d_ws;   // 28 * 65536 * 4 = 7.34 MB

  // Phase 1: 256 pixel-blocks x 2 streams = 512 blocks (2/CU), 256 px each
  proj_kernel<<<dim3(NPIX / PX, 2), dim3(256), 0, stream>>>(P);
  // Phase 2: 256 pixel-blocks x 9 output nodes
  gnn_node<<<dim3(NPIX / 256, 9), dim3(256), 0, stream>>>(P);
}

// Round 9
// 70.331 us; speedup vs baseline: 1.6714x; 1.6714x over previous
//
#include <hip/hip_runtime.h>

// GNN_51539607552576 — round 9.
// Phase 1 (proj): inline-asm 8-deep load ring, FIXED:
//   * "=&v" early-clobber (R8 bug: dest aliased voff -> address corruption)
//   * weights preloaded to LDS (transposed [ch][o]) -> steady-state loop has
//     ZERO compiler vmem; counted s_waitcnt vmcnt(7) is sound
//   * sched_barrier(0) after each wait (rule #18)
//   * 2-pass conflict-free LDS reduce (stride 33), 50.2 KB -> 2 blocks/CU
// Phase 2 (gnn_node): unchanged (per-output-node split, ~10 us).

namespace {
constexpr int S     = 128 * 128;
constexpr int BATCH = 4;
constexpr int HID   = 10;
constexpr int INDIM = 256;
constexpr int NPIX  = BATCH * S;   // 65536

typedef float f32x4 __attribute__((ext_vector_type(4)));

constexpr unsigned CHB  = S * 4;   // channel stride in bytes
constexpr int WOFF      = 0;       // weights: lds[0 .. 4096)
constexpr int ROFF      = 4096;    // reduce buffer: 256 rows x 33 floats
constexpr int RSTR      = 33;      // 33 % 32 == 1 -> conflict-free b32
constexpr int LDS_FLOATS = ROFF + 256 * RSTR;   // 12544 floats = 50.2 KB

struct Ptrs {
  const float* __restrict__ xp;
  const float* __restrict__ xh;
  const float* __restrict__ xf;
  const float* __restrict__ p_fea;
  const float* __restrict__ h_fea;
  const float* __restrict__ Wf_comp;  const float* __restrict__ bf_comp;
  const float* __restrict__ Wf_uatt;  const float* __restrict__ bf_uatt;
  const float* __restrict__ Wf_uupd;
  const float* __restrict__ Wh_pdp_f; const float* __restrict__ Wh_pdp_x;
  const float* __restrict__ bh_pdp;
  const float* __restrict__ Wh_att;   const float* __restrict__ bh_att;
  const float* __restrict__ Wh_cu;    const float* __restrict__ bh_cu;
  const float* __restrict__ Wh_cl;    const float* __restrict__ bh_cl;
  const float* __restrict__ Wh_dec_f; const float* __restrict__ Wh_dec_x;
  const float* __restrict__ bh_dec;
  const float* __restrict__ Wh_uatt;  const float* __restrict__ bh_uatt;
  const float* __restrict__ Wh_uupd;
  const float* __restrict__ Wp_pdp_f; const float* __restrict__ Wp_pdp_x;
  const float* __restrict__ bp_pdp;
  const float* __restrict__ Wp_att;   const float* __restrict__ bp_att;
  const float* __restrict__ Wp_dec_f; const float* __restrict__ Wp_dec_x;
  const float* __restrict__ bp_dec;
  const float* __restrict__ Wp_uatt;  const float* __restrict__ bp_uatt;
  const float* __restrict__ Wp_uupd;
  float* __restrict__ out;
  float* __restrict__ ws;
};

__device__ __forceinline__ float sigmoidf(float x) {
  return 1.0f / (1.0f + __expf(-x));
}

// ============================ Phase 1: projections ============================
// ws rows: 0..9 fh, 10..11 hdec, 12..21 fpj, 22..27 pdec. Column = pixel id.
// Block: 256 thr = 64 px-groups (float4) x 4 slice-waves (64 ch each).
// Grid: (256 tiles, 2 streams) = 512 blocks = 2/CU = 8 waves/CU.

#define ISSUE(i)                                                        \
  asm volatile("global_load_dwordx4 %0, %1, %2"                        \
               : "=&v"(r[i]) : "v"(voff[i]), "s"(sbase) : "memory")
#define WAIT7  do { asm volatile("s_waitcnt vmcnt(7)" ::: "memory");    \
                    __builtin_amdgcn_sched_barrier(0); } while (0)

template <int NO>  // 12 (h stream) or 16 (p stream)
__device__ __forceinline__ void proj_impl(
    float* lds,
    const float* __restrict__ fea,
    const float* __restrict__ Wa,         // [10][INDIM]
    const float* __restrict__ Wb,         // [NO-10][INDIM]
    float* __restrict__ ws, int obase) {
  const int t   = threadIdx.x;
  const int pxg = t & 63;
  const int sl  = __builtin_amdgcn_readfirstlane(t >> 6);
  const int pb  = blockIdx.x * 256;
  const int b   = pb >> 14;
  const int p0  = pb & (S - 1);

  // ---- preload weights to LDS, transposed: lds_w[ch*NO + o] = W[o][ch] ----
  float* lds_w = lds + WOFF;
  for (int i = t; i < NO * INDIM; i += 256) {
    const int o = i >> 8, ch = i & 255;
    const float wv = (o < 10) ? Wa[o * INDIM + ch] : Wb[(o - 10) * INDIM + ch];
    lds_w[ch * NO + o] = wv;
  }
  __syncthreads();   // drains vmcnt/lgkmcnt -> clean counter state

  f32x4 acc[NO];
#pragma unroll
  for (int o = 0; o < NO; ++o) acc[o] = (f32x4){0.f, 0.f, 0.f, 0.f};

  const uint64_t sbase =
      (uint64_t)(fea + (size_t)(b * INDIM + sl * 64) * S + p0);

  // ---- 8-deep explicit load ring: the ONLY vmem ops until the final stores --
  f32x4    r[8];
  unsigned voff[8];
#pragma unroll
  for (int i = 0; i < 8; ++i) {
    voff[i] = (unsigned)i * CHB + (unsigned)(pxg * 16);
    ISSUE(i);
  }

#pragma unroll 1
  for (int blk = 0; blk < 7; ++blk) {      // channels 0..55, with reissue
#pragma unroll
    for (int i = 0; i < 8; ++i) {
      WAIT7;
      const f32x4 v = r[i];
      const int ch = blk * 8 + i;          // local channel (weights indexed by sl*64+ch)
      const float* wrow = lds_w + (size_t)(sl * 64 + ch) * NO;
#pragma unroll
      for (int g = 0; g < NO / 4; ++g) {
        const f32x4 w4 = *(const f32x4*)(wrow + 4 * g);   // ds_read_b128 bcast
        acc[4 * g + 0] += v * w4.x;
        acc[4 * g + 1] += v * w4.y;
        acc[4 * g + 2] += v * w4.z;
        acc[4 * g + 3] += v * w4.w;
      }
      voff[i] += 8u * CHB;
      ISSUE(i);
    }
  }
#pragma unroll
  for (int i = 0; i < 8; ++i) {            // epilogue: channels 56..63
    if      (i == 0) asm volatile("s_waitcnt vmcnt(7)" ::: "memory");
    else if (i == 1) asm volatile("s_waitcnt vmcnt(6)" ::: "memory");
    else if (i == 2) asm volatile("s_waitcnt vmcnt(5)" ::: "memory");
    else if (i == 3) asm volatile("s_waitcnt vmcnt(4)" ::: "memory");
    else if (i == 4) asm volatile("s_waitcnt vmcnt(3)" ::: "memory");
    else if (i == 5) asm volatile("s_waitcnt vmcnt(2)" ::: "memory");
    else if (i == 6) asm volatile("s_waitcnt vmcnt(1)" ::: "memory");
    else             asm volatile("s_waitcnt vmcnt(0)" ::: "memory");
    __builtin_amdgcn_sched_barrier(0);
    const f32x4 v = r[i];
    const int ch = 56 + i;
    const float* wrow = lds_w + (size_t)(sl * 64 + ch) * NO;
#pragma unroll
    for (int g = 0; g < NO / 4; ++g) {
      const f32x4 w4 = *(const f32x4*)(wrow + 4 * g);
      acc[4 * g + 0] += v * w4.x;
      acc[4 * g + 1] += v * w4.y;
      acc[4 * g + 2] += v * w4.z;
      acc[4 * g + 3] += v * w4.w;
    }
  }

  // ---- two-pass cross-wave reduce (conflict-free: stride 33, b32 ops) ----
  float* red = lds + ROFF;
  const int og = t >> 6;
#pragma unroll 1
  for (int pass = 0; pass < 2; ++pass) {
    const int o0 = pass * 8;
    const int NP = (pass == 0) ? 8 : (NO - 8);   // 8 then 4 (h) / 8 (p)
    __syncthreads();                              // prev pass reads done
    float* row = red + (sl * 64 + pxg) * RSTR;
    for (int k = 0; k < NP; ++k) {
      const f32x4 a = acc[o0 + k];
      row[4 * k + 0] = a.x; row[4 * k + 1] = a.y;
      row[4 * k + 2] = a.z; row[4 * k + 3] = a.w;
    }
    __syncthreads();
    // og-group reduces NP/4 outputs (pass B h-stream: only og 0 active)
    const int K = NP / 4;
    for (int k = 0; k < K; ++k) {
      const int lo = og * K + k;                  // local output in pass
      float rsum[4] = {0.f, 0.f, 0.f, 0.f};
#pragma unroll
      for (int s2 = 0; s2 < 4; ++s2) {
        const float* rp = red + (s2 * 64 + pxg) * RSTR + 4 * lo;
#pragma unroll
        for (int j = 0; j < 4; ++j) rsum[j] += rp[j];
      }
      float4 res; res.x = rsum[0]; res.y = rsum[1]; res.z = rsum[2]; res.w = rsum[3];
      *(float4*)(ws + (size_t)(obase + o0 + lo) * NPIX + pb + pxg * 4) = res;
    }
  }
}

__global__ __launch_bounds__(256, 2) void proj_kernel(Ptrs P) {
  __shared__ float lds[LDS_FLOATS];   // 50.2 KB -> 2 blocks/CU (LDS) ok
  if (blockIdx.y == 0) {
    proj_impl<12>(lds, P.h_fea, P.Wh_pdp_f, P.Wh_dec_f, P.ws, 0);
  } else {
    proj_impl<16>(lds, P.p_fea, P.Wp_pdp_f, P.Wp_dec_f, P.ws, 12);
  }
}

// ============================ Phase 2: per-node graph math ============================

__device__ __forceinline__ void att_update_store(
    const float* x, const float* m,
    const float* __restrict__ Wa, float ba, const float* __restrict__ Wu,
    float* __restrict__ outp) {
  float a = ba;
#pragma unroll
  for (int c = 0; c < HID; ++c) a = fmaf(x[c], Wa[c], a);
#pragma unroll
  for (int c = 0; c < HID; ++c) a = fmaf(m[c], Wa[HID + c], a);
  a = sigmoidf(a);
#pragma unroll
  for (int o = 0; o < HID; ++o) {
    float u = 0.f;
#pragma unroll
    for (int c = 0; c < HID; ++c) u = fmaf(x[c], Wu[o * 2 * HID + c], u);
#pragma unroll
    for (int c = 0; c < HID; ++c) u = fmaf(m[c], Wu[o * 2 * HID + HID + c], u);
    u = fmaxf(u, 0.f);
    outp[(size_t)o * S] = x[o] * (1.f - a) + u * a;
  }
}

__device__ __forceinline__ void load10(float* dst, const float* __restrict__ src,
                                       int plane, int p) {
#pragma unroll
  for (int c = 0; c < HID; ++c)
    dst[c] = src[((size_t)plane * HID + c) * S + p];
}

// grid.y = node id: 0..5 parts, 6..7 halves, 8 full
__global__ __launch_bounds__(256) void gnn_node(Ptrs P) {
  const int tid = blockIdx.x * blockDim.x + threadIdx.x;
  const int b = tid >> 14;
  const int p = tid & (S - 1);
  const int y = blockIdx.y;

  if (y == 8) {
    // ---------------- full graph ----------------
    float xh0[HID], xh1[HID], xfv[HID];
    load10(xh0, P.xh, 0 * BATCH + b, p);
    load10(xh1, P.xh, 1 * BATCH + b, p);
    load10(xfv, P.xf, b, p);
    float a0 = P.bf_comp[0], a1 = P.bf_comp[1];
#pragma unroll
    for (int c = 0; c < HID; ++c) {
      a0 = fmaf(xh0[c], P.Wf_comp[c], a0);
      a1 = fmaf(xh1[c], P.Wf_comp[HID + c], a1);
    }
    a0 = sigmoidf(a0); a1 = sigmoidf(a1);
    float msg[HID];
#pragma unroll
    for (int c = 0; c < HID; ++c) msg[c] = a0 * xh0[c] + a1 * xh1[c];
    att_update_store(xfv, msg, P.Wf_uatt, P.bf_uatt[0], P.Wf_uupd,
                     P.out + ((size_t)(8 * BATCH + b) * HID) * S + p);
  } else if (y >= 6) {
    // ---------------- half graph, node h ----------------
    const int h = y - 6;
    float xh_self[HID], xh_oth[HID], xfv[HID], fh[HID];
    load10(xh_self, P.xh, h * BATCH + b, p);
    load10(xh_oth,  P.xh, (1 - h) * BATCH + b, p);
    load10(xfv, P.xf, b, p);
#pragma unroll
    for (int o = 0; o < HID; ++o) fh[o] = P.ws[(size_t)o * NPIX + tid];
    const float hdec = P.ws[(size_t)(10 + h) * NPIX + tid];

    const int nsrc = h ? 2 : 4;
    const int sbase2 = h ? 4 : 0;
    const float* __restrict__ Wc = h ? P.Wh_cl : P.Wh_cu;
    const float* __restrict__ bc = h ? P.bh_cl : P.bh_cu;
    float comp[HID];
#pragma unroll
    for (int o = 0; o < HID; ++o) comp[o] = 0.f;
#pragma unroll
    for (int i = 0; i < 4; ++i) {
      if (i < nsrc) {
        float xpi[HID];
        load10(xpi, P.xp, (sbase2 + i) * BATCH + b, p);
        float s = bc[i];
#pragma unroll
        for (int c = 0; c < HID; ++c) s = fmaf(xpi[c], Wc[i * HID + c], s);
        s = sigmoidf(s);
#pragma unroll
        for (int c = 0; c < HID; ++c) comp[c] = fmaf(s, xpi[c], comp[c]);
      }
    }

    float a_self = P.bh_att[h], a_oth = P.bh_att[1 - h];
#pragma unroll
    for (int c = 0; c < HID; ++c) {
      a_self = fmaf(xh_self[c], P.Wh_att[h * HID + c], a_self);
      a_oth  = fmaf(xh_oth[c],  P.Wh_att[(1 - h) * HID + c], a_oth);
    }
    a_self = sigmoidf(a_self); a_oth = sigmoidf(a_oth);
    const float wg = a_oth * (1.f - a_self);

    float d = hdec + P.bh_dec[h];
#pragma unroll
    for (int c = 0; c < HID; ++c) d = fmaf(xh_self[c], P.Wh_dec_x[h * HID + c], d);
    d = sigmoidf(d);

    float m[HID];
#pragma unroll
    for (int o = 0; o < HID; ++o) {
      float dp = fh[o] + P.bh_pdp[o];
#pragma unroll
      for (int c = 0; c < HID; ++c) dp = fmaf(xh_oth[c], P.Wh_pdp_x[o * HID + c], dp);
      dp = fmaxf(dp, 0.f);
      m[o] = comp[o] + dp * wg + d * xfv[o];
    }
    att_update_store(xh_self, m, P.Wh_uatt + h * 2 * HID, P.bh_uatt[h],
                     P.Wh_uupd + h * HID * 2 * HID,
                     P.out + ((size_t)((6 + h) * BATCH + b) * HID) * S + p);
  } else {
    // ---------------- part graph, node n ----------------
    const int n = y;
    const int half = (n < 4) ? 0 : 1;
    // ADJ columns: dst0{1} dst1{0,2,3,4,5} dst2{1} dst3{1} dst4{1,5} dst5{1,4}
    const unsigned masks[6] = {0x02u, 0x3Du, 0x02u, 0x02u, 0x22u, 0x12u};
    const unsigned mask = masks[n];

    float xpn[HID], xh_s[HID], fpj[HID];
    load10(xpn, P.xp, n * BATCH + b, p);
    load10(xh_s, P.xh, half * BATCH + b, p);
#pragma unroll
    for (int o = 0; o < HID; ++o) fpj[o] = P.ws[(size_t)(12 + o) * NPIX + tid];
    const float pdecn = P.ws[(size_t)(22 + n) * NPIX + tid];

    float pattn = P.bp_att[n];
#pragma unroll
    for (int c = 0; c < HID; ++c) pattn = fmaf(xpn[c], P.Wp_att[n * HID + c], pattn);
    pattn = sigmoidf(pattn);

    float msum[HID];
#pragma unroll
    for (int o = 0; o < HID; ++o) msum[o] = 0.f;
#pragma unroll
    for (int src = 0; src < 6; ++src) {
      if (mask & (1u << src)) {
        float xps[HID];
        load10(xps, P.xp, src * BATCH + b, p);
        float ps = P.bp_att[src];
#pragma unroll
        for (int c = 0; c < HID; ++c) ps = fmaf(xps[c], P.Wp_att[src * HID + c], ps);
        ps = sigmoidf(ps);
#pragma unroll
        for (int o = 0; o < HID; ++o) {
          float dp = fpj[o] + P.bp_pdp[o];
#pragma unroll
          for (int c = 0; c < HID; ++c) dp = fmaf(xps[c], P.Wp_pdp_x[o * HID + c], dp);
          msum[o] = fmaf(fmaxf(dp, 0.f), ps, msum[o]);
        }
      }
    }

    float dg = pdecn + P.bp_dec[n];
#pragma unroll
    for (int c = 0; c < HID; ++c) dg = fmaf(xpn[c], P.Wp_dec_x[n * HID + c], dg);
    dg = sigmoidf(dg);

    const float onem = 1.f - pattn;
    float m[HID];
#pragma unroll
    for (int o = 0; o < HID; ++o) m[o] = onem * msum[o] + dg * xh_s[o];

    att_update_store(xpn, m, P.Wp_uatt + n * 2 * HID, P.bp_uatt[n],
                     P.Wp_uupd + n * HID * 2 * HID,
                     P.out + ((size_t)(n * BATCH + b) * HID) * S + p);
  }
}

}  // namespace

extern "C" void kernel_launch(void* const* d_in, const int* in_sizes, int n_in,
                              void* d_out, int out_size, void* d_ws, size_t ws_size,
                              hipStream_t stream) {
  Ptrs P;
  P.xp       = (const float*)d_in[0];
  P.xh       = (const float*)d_in[1];
  P.xf       = (const float*)d_in[2];
  // d_in[3] = bg_node (unused)
  P.p_fea    = (const float*)d_in[4];
  P.h_fea    = (const float*)d_in[5];
  // d_in[6] = f_fea (unused)
  P.Wf_comp  = (const float*)d_in[7];
  P.bf_comp  = (const float*)d_in[8];
  P.Wf_uatt  = (const float*)d_in[9];
  P.bf_uatt  = (const float*)d_in[10];
  P.Wf_uupd  = (const float*)d_in[11];
  P.Wh_pdp_f = (const float*)d_in[12];
  P.Wh_pdp_x = (const float*)d_in[13];
  P.bh_pdp   = (const float*)d_in[14];
  P.Wh_att   = (const float*)d_in[15];
  P.bh_att   = (const float*)d_in[16];
  P.Wh_cu    = (const float*)d_in[17];
  P.bh_cu    = (const float*)d_in[18];
  P.Wh_cl    = (const float*)d_in[19];
  P.bh_cl    = (const float*)d_in[20];
  P.Wh_dec_f = (const float*)d_in[21];
  P.Wh_dec_x = (const float*)d_in[22];
  P.bh_dec   = (const float*)d_in[23];
  P.Wh_uatt  = (const float*)d_in[24];
  P.bh_uatt  = (const float*)d_in[25];
  P.Wh_uupd  = (const float*)d_in[26];
  P.Wp_pdp_f = (const float*)d_in[27];
  P.Wp_pdp_x = (const float*)d_in[28];
  P.bp_pdp   = (const float*)d_in[29];
  P.Wp_att   = (const float*)d_in[30];
  P.bp_att   = (const float*)d_in[31];
  P.Wp_dec_f = (const float*)d_in[32];
  P.Wp_dec_x = (const float*)d_in[33];
  P.bp_dec   = (const float*)d_in[34];
  P.Wp_uatt  = (const float*)d_in[35];
  P.bp_uatt  = (const float*)d_in[36];
  P.Wp_uupd  = (const float*)d_in[37];
  P.out      = (float*)d_out;
  P.ws       = (float*)d_ws;   // 28 * 65536 * 4 = 7.34 MB

  // Phase 1: 256 pixel-tiles x 2 streams = 512 blocks, 256 px per block
  proj_kernel<<<dim3(NPIX / 256, 2), dim3(256), 0, stream>>>(P);
  // Phase 2: 256 pixel-blocks x 9 output nodes
  gnn_node<<<dim3(NPIX / 256, 9), dim3(256), 0, stream>>>(P);
}

// Round 10
// 69.393 us; speedup vs baseline: 1.6940x; 1.0135x over previous
//
#include <hip/hip_runtime.h>

// GNN_51539607552576 — round 10: single fused kernel.
// Each block: R6-style proj (16-deep ring, float4, 4 slice-waves, LDS reduce)
//   then IN-KERNEL graph math for the nodes that need only its stream:
//   y==0 (h_fea): fh/hdec -> full node + 2 half nodes (out planes 6,7,8)
//   y==1 (p_fea): fpj/pdec -> 6 part nodes            (out planes 0..5)
// ws round-trip eliminated; gnn work hides under proj memory stalls.

namespace {
constexpr int S     = 128 * 128;
constexpr int BATCH = 4;
constexpr int HID   = 10;
constexpr int INDIM = 256;
constexpr int NPIX  = BATCH * S;   // 65536

constexpr int LROW = 65;   // LDS reduce row stride (odd -> conflict-free)
constexpr int RD   = 16;   // ring depth

struct Ptrs {
  const float* __restrict__ xp;
  const float* __restrict__ xh;
  const float* __restrict__ xf;
  const float* __restrict__ p_fea;
  const float* __restrict__ h_fea;
  const float* __restrict__ Wf_comp;  const float* __restrict__ bf_comp;
  const float* __restrict__ Wf_uatt;  const float* __restrict__ bf_uatt;
  const float* __restrict__ Wf_uupd;
  const float* __restrict__ Wh_pdp_f; const float* __restrict__ Wh_pdp_x;
  const float* __restrict__ bh_pdp;
  const float* __restrict__ Wh_att;   const float* __restrict__ bh_att;
  const float* __restrict__ Wh_cu;    const float* __restrict__ bh_cu;
  const float* __restrict__ Wh_cl;    const float* __restrict__ bh_cl;
  const float* __restrict__ Wh_dec_f; const float* __restrict__ Wh_dec_x;
  const float* __restrict__ bh_dec;
  const float* __restrict__ Wh_uatt;  const float* __restrict__ bh_uatt;
  const float* __restrict__ Wh_uupd;
  const float* __restrict__ Wp_pdp_f; const float* __restrict__ Wp_pdp_x;
  const float* __restrict__ bp_pdp;
  const float* __restrict__ Wp_att;   const float* __restrict__ bp_att;
  const float* __restrict__ Wp_dec_f; const float* __restrict__ Wp_dec_x;
  const float* __restrict__ bp_dec;
  const float* __restrict__ Wp_uatt;  const float* __restrict__ bp_uatt;
  const float* __restrict__ Wp_uupd;
  float* __restrict__ out;
};

__device__ __forceinline__ float sigmoidf(float x) {
  return 1.0f / (1.0f + __expf(-x));
}

// ---- projection: 256 px/block, 4 slice-waves x 64 ch, ring prefetch ----
// Result: pr[o] = projection output o for pixel (blockIdx.x*256 + threadIdx.x)
template <int NO>  // 12 (h) or 16 (p)
__device__ __forceinline__ void proj_to_reg(
    float* lds,
    const float* __restrict__ fea,
    const float* __restrict__ Wa,         // [10][INDIM]
    const float* __restrict__ Wb,         // [NO-10][INDIM]
    float* __restrict__ pr) {
  const int t   = threadIdx.x;
  const int pxg = t & 63;
  const int sl  = __builtin_amdgcn_readfirstlane(t >> 6);
  const int pb  = blockIdx.x * 256;
  const int b   = pb >> 14;
  const int p0  = pb & (S - 1);
  const size_t S4 = S / 4;

  float4 acc[NO];
#pragma unroll
  for (int o = 0; o < NO; ++o) acc[o] = float4{0.f, 0.f, 0.f, 0.f};

  const float4* __restrict__ base =
      (const float4*)(fea + (size_t)(b * INDIM + sl * 64) * S + p0) + pxg;

  float4 ring[RD];
#pragma unroll
  for (int i = 0; i < RD; ++i) ring[i] = base[(size_t)i * S4];

#pragma unroll 1
  for (int cb = 0; cb < 64 - RD; cb += RD) {   // cb = 0, 16, 32
#pragma unroll
    for (int i = 0; i < RD; ++i) {
      const float4 v = ring[i];
      ring[i] = base[(size_t)(cb + RD + i) * S4];
      const int c = sl * 64 + cb + i;
#pragma unroll
      for (int o = 0; o < 10; ++o) {
        const float w = Wa[o * INDIM + c];
        acc[o].x = fmaf(v.x, w, acc[o].x);
        acc[o].y = fmaf(v.y, w, acc[o].y);
        acc[o].z = fmaf(v.z, w, acc[o].z);
        acc[o].w = fmaf(v.w, w, acc[o].w);
      }
#pragma unroll
      for (int o = 10; o < NO; ++o) {
        const float w = Wb[(o - 10) * INDIM + c];
        acc[o].x = fmaf(v.x, w, acc[o].x);
        acc[o].y = fmaf(v.y, w, acc[o].y);
        acc[o].z = fmaf(v.z, w, acc[o].z);
        acc[o].w = fmaf(v.w, w, acc[o].w);
      }
    }
  }
#pragma unroll
  for (int i = 0; i < RD; ++i) {               // epilogue: last 16 channels
    const float4 v = ring[i];
    const int c = sl * 64 + (64 - RD) + i;
#pragma unroll
    for (int o = 0; o < 10; ++o) {
      const float w = Wa[o * INDIM + c];
      acc[o].x = fmaf(v.x, w, acc[o].x);
      acc[o].y = fmaf(v.y, w, acc[o].y);
      acc[o].z = fmaf(v.z, w, acc[o].z);
      acc[o].w = fmaf(v.w, w, acc[o].w);
    }
#pragma unroll
    for (int o = 10; o < NO; ++o) {
      const float w = Wb[(o - 10) * INDIM + c];
      acc[o].x = fmaf(v.x, w, acc[o].x);
      acc[o].y = fmaf(v.y, w, acc[o].y);
      acc[o].z = fmaf(v.z, w, acc[o].z);
      acc[o].w = fmaf(v.w, w, acc[o].w);
    }
  }

  // ---- cross-wave reduce ----
  float* row = lds + (sl * 64 + pxg) * LROW;
#pragma unroll
  for (int o = 0; o < NO; ++o) {
    row[4 * o + 0] = acc[o].x;
    row[4 * o + 1] = acc[o].y;
    row[4 * o + 2] = acc[o].z;
    row[4 * o + 3] = acc[o].w;
  }
  __syncthreads();

  constexpr int K = NO / 4;
  const int og = t >> 6;
  float4 res[K];
#pragma unroll
  for (int k = 0; k < K; ++k) {
    const int o = og * K + k;
    float rr[4] = {0.f, 0.f, 0.f, 0.f};
#pragma unroll
    for (int s2 = 0; s2 < 4; ++s2) {
      const float* rp = lds + (s2 * 64 + pxg) * LROW + 4 * o;
#pragma unroll
      for (int j = 0; j < 4; ++j) rr[j] += rp[j];
    }
    res[k] = float4{rr[0], rr[1], rr[2], rr[3]};
  }
  __syncthreads();   // all reduce reads done -> safe to overwrite lds

  // ---- redistribute: lds[o*256 + i] = output o of pixel pb+i ----
#pragma unroll
  for (int k = 0; k < K; ++k) {
    const int o = og * K + k;
    *(float4*)(lds + o * 256 + pxg * 4) = res[k];
  }
  __syncthreads();
#pragma unroll
  for (int o = 0; o < NO; ++o) pr[o] = lds[o * 256 + t];
}

__device__ __forceinline__ void att_update_store(
    const float* x, const float* m,
    const float* __restrict__ Wa, float ba, const float* __restrict__ Wu,
    float* __restrict__ outp) {
  float a = ba;
#pragma unroll
  for (int c = 0; c < HID; ++c) a = fmaf(x[c], Wa[c], a);
#pragma unroll
  for (int c = 0; c < HID; ++c) a = fmaf(m[c], Wa[HID + c], a);
  a = sigmoidf(a);
#pragma unroll
  for (int o = 0; o < HID; ++o) {
    float u = 0.f;
#pragma unroll
    for (int c = 0; c < HID; ++c) u = fmaf(x[c], Wu[o * 2 * HID + c], u);
#pragma unroll
    for (int c = 0; c < HID; ++c) u = fmaf(m[c], Wu[o * 2 * HID + HID + c], u);
    u = fmaxf(u, 0.f);
    outp[(size_t)o * S] = x[o] * (1.f - a) + u * a;
  }
}

__device__ __forceinline__ void load10(float* dst, const float* __restrict__ src,
                                       int plane, int p) {
#pragma unroll
  for (int c = 0; c < HID; ++c)
    dst[c] = src[((size_t)plane * HID + c) * S + p];
}

__global__ __launch_bounds__(256, 2) void gnn_fused(Ptrs P) {
  __shared__ float lds[256 * LROW];   // 66.6 KB -> 2 blocks/CU
  const int t  = threadIdx.x;
  const int pb = blockIdx.x * 256;
  const int b  = pb >> 14;
  const int p  = (pb & (S - 1)) + t;

  if (blockIdx.y == 0) {
    // ================= h-stream: proj + full node + half nodes =================
    float pr[12];   // 0..9 fh, 10..11 hdec
    proj_to_reg<12>(lds, P.h_fea, P.Wh_pdp_f, P.Wh_dec_f, pr);

    float xh0[HID], xh1[HID], xfv[HID];
    load10(xh0, P.xh, 0 * BATCH + b, p);
    load10(xh1, P.xh, 1 * BATCH + b, p);
    load10(xfv, P.xf, b, p);

    // ---- full graph ----
    {
      float a0 = P.bf_comp[0], a1 = P.bf_comp[1];
#pragma unroll
      for (int c = 0; c < HID; ++c) {
        a0 = fmaf(xh0[c], P.Wf_comp[c], a0);
        a1 = fmaf(xh1[c], P.Wf_comp[HID + c], a1);
      }
      a0 = sigmoidf(a0); a1 = sigmoidf(a1);
      float msg[HID];
#pragma unroll
      for (int c = 0; c < HID; ++c) msg[c] = a0 * xh0[c] + a1 * xh1[c];
      att_update_store(xfv, msg, P.Wf_uatt, P.bf_uatt[0], P.Wf_uupd,
                       P.out + ((size_t)(8 * BATCH + b) * HID) * S + p);
    }

    // ---- half graph (both halves) ----
    {
      float hatt0 = P.bh_att[0], hatt1 = P.bh_att[1];
#pragma unroll
      for (int c = 0; c < HID; ++c) {
        hatt0 = fmaf(xh0[c], P.Wh_att[c], hatt0);
        hatt1 = fmaf(xh1[c], P.Wh_att[HID + c], hatt1);
      }
      hatt0 = sigmoidf(hatt0); hatt1 = sigmoidf(hatt1);

      float xphu[HID] = {}, xphl[HID] = {};
#pragma unroll
      for (int i = 0; i < 4; ++i) {
        float xpi[HID];
        load10(xpi, P.xp, i * BATCH + b, p);
        float s = P.bh_cu[i];
#pragma unroll
        for (int c = 0; c < HID; ++c) s = fmaf(xpi[c], P.Wh_cu[i * HID + c], s);
        s = sigmoidf(s);
#pragma unroll
        for (int c = 0; c < HID; ++c) xphu[c] = fmaf(s, xpi[c], xphu[c]);
      }
#pragma unroll
      for (int i = 0; i < 2; ++i) {
        float xpi[HID];
        load10(xpi, P.xp, (4 + i) * BATCH + b, p);
        float s = P.bh_cl[i];
#pragma unroll
        for (int c = 0; c < HID; ++c) s = fmaf(xpi[c], P.Wh_cl[i * HID + c], s);
        s = sigmoidf(s);
#pragma unroll
        for (int c = 0; c < HID; ++c) xphl[c] = fmaf(s, xpi[c], xphl[c]);
      }

      float d0 = pr[10] + P.bh_dec[0], d1 = pr[11] + P.bh_dec[1];
#pragma unroll
      for (int c = 0; c < HID; ++c) {
        d0 = fmaf(xh0[c], P.Wh_dec_x[c], d0);
        d1 = fmaf(xh1[c], P.Wh_dec_x[HID + c], d1);
      }
      d0 = sigmoidf(d0); d1 = sigmoidf(d1);

      const float wl = hatt1 * (1.f - hatt0);   // gates dp(xh1) into msg0
      const float wu = hatt0 * (1.f - hatt1);   // gates dp(xh0) into msg1

      float m0[HID], m1[HID];
#pragma unroll
      for (int o = 0; o < HID; ++o) {
        const float base_o = pr[o] + P.bh_pdp[o];
        float dp0 = base_o, dp1 = base_o;
#pragma unroll
        for (int c = 0; c < HID; ++c) {
          dp0 = fmaf(xh0[c], P.Wh_pdp_x[o * HID + c], dp0);
          dp1 = fmaf(xh1[c], P.Wh_pdp_x[o * HID + c], dp1);
        }
        dp0 = fmaxf(dp0, 0.f);
        dp1 = fmaxf(dp1, 0.f);
        m0[o] = xphu[o] + dp1 * wl + d0 * xfv[o];
        m1[o] = xphl[o] + dp0 * wu + d1 * xfv[o];
      }
      att_update_store(xh0, m0, P.Wh_uatt, P.bh_uatt[0], P.Wh_uupd,
                       P.out + ((size_t)(6 * BATCH + b) * HID) * S + p);
      att_update_store(xh1, m1, P.Wh_uatt + 2 * HID, P.bh_uatt[1],
                       P.Wh_uupd + HID * 2 * HID,
                       P.out + ((size_t)(7 * BATCH + b) * HID) * S + p);
    }
  } else {
    // ================= p-stream: proj + 6 part nodes =================
    float pr[16];   // 0..9 fpj, 10..15 pdec
    proj_to_reg<16>(lds, P.p_fea, P.Wp_pdp_f, P.Wp_dec_f, pr);

    float xh0[HID], xh1[HID];
    load10(xh0, P.xh, 0 * BATCH + b, p);
    load10(xh1, P.xh, 1 * BATCH + b, p);

    // attention gates for all 6 parts
    float patt[6];
#pragma unroll
    for (int n = 0; n < 6; ++n) {
      float xpn[HID];
      load10(xpn, P.xp, n * BATCH + b, p);
      float s = P.bp_att[n];
#pragma unroll
      for (int c = 0; c < HID; ++c) s = fmaf(xpn[c], P.Wp_att[n * HID + c], s);
      patt[n] = sigmoidf(s);
    }

    // gated source messages g[n]; segment sums via ADJ columns:
    // dst0,2,3 <- g1 ; dst1 <- g0+g2+g3+g4+g5 ; dst4 <- g1+g5 ; dst5 <- g1+g4
    float g1[HID], gOth[HID] = {}, g4[HID], g5[HID];
#pragma unroll
    for (int n = 0; n < 6; ++n) {
      float xpn[HID];
      load10(xpn, P.xp, n * BATCH + b, p);
#pragma unroll
      for (int o = 0; o < HID; ++o) {
        float dp = pr[o] + P.bp_pdp[o];
#pragma unroll
        for (int c = 0; c < HID; ++c) dp = fmaf(xpn[c], P.Wp_pdp_x[o * HID + c], dp);
        dp = fmaxf(dp, 0.f) * patt[n];
        if (n == 1) g1[o] = dp; else gOth[o] += dp;
        if (n == 4) g4[o] = dp;
        if (n == 5) g5[o] = dp;
      }
    }

#pragma unroll
    for (int n = 0; n < 6; ++n) {
      float xpn[HID];
      load10(xpn, P.xp, n * BATCH + b, p);
      const float onem = 1.f - patt[n];
      float dg = pr[10 + n] + P.bp_dec[n];
#pragma unroll
      for (int c = 0; c < HID; ++c) dg = fmaf(xpn[c], P.Wp_dec_x[n * HID + c], dg);
      dg = sigmoidf(dg);

      float m[HID];
#pragma unroll
      for (int o = 0; o < HID; ++o) {
        float sum;
        if (n == 0 || n == 2 || n == 3) sum = g1[o];
        else if (n == 1)                sum = gOth[o];
        else if (n == 4)                sum = g1[o] + g5[o];
        else                            sum = g1[o] + g4[o];
        const float xh_src = (n < 4) ? xh0[o] : xh1[o];   // HALF_IDX
        m[o] = onem * sum + dg * xh_src;
      }
      att_update_store(xpn, m, P.Wp_uatt + n * 2 * HID, P.bp_uatt[n],
                       P.Wp_uupd + n * HID * 2 * HID,
                       P.out + ((size_t)(n * BATCH + b) * HID) * S + p);
    }
  }
}

}  // namespace

extern "C" void kernel_launch(void* const* d_in, const int* in_sizes, int n_in,
                              void* d_out, int out_size, void* d_ws, size_t ws_size,
                              hipStream_t stream) {
  Ptrs P;
  P.xp       = (const float*)d_in[0];
  P.xh       = (const float*)d_in[1];
  P.xf       = (const float*)d_in[2];
  // d_in[3] = bg_node (unused)
  P.p_fea    = (const float*)d_in[4];
  P.h_fea    = (const float*)d_in[5];
  // d_in[6] = f_fea (unused)
  P.Wf_comp  = (const float*)d_in[7];
  P.bf_comp  = (const float*)d_in[8];
  P.Wf_uatt  = (const float*)d_in[9];
  P.bf_uatt  = (const float*)d_in[10];
  P.Wf_uupd  = (const float*)d_in[11];
  P.Wh_pdp_f = (const float*)d_in[12];
  P.Wh_pdp_x = (const float*)d_in[13];
  P.bh_pdp   = (const float*)d_in[14];
  P.Wh_att   = (const float*)d_in[15];
  P.bh_att   = (const float*)d_in[16];
  P.Wh_cu    = (const float*)d_in[17];
  P.bh_cu    = (const float*)d_in[18];
  P.Wh_cl    = (const float*)d_in[19];
  P.bh_cl    = (const float*)d_in[20];
  P.Wh_dec_f = (const float*)d_in[21];
  P.Wh_dec_x = (const float*)d_in[22];
  P.bh_dec   = (const float*)d_in[23];
  P.Wh_uatt  = (const float*)d_in[24];
  P.bh_uatt  = (const float*)d_in[25];
  P.Wh_uupd  = (const float*)d_in[26];
  P.Wp_pdp_f = (const float*)d_in[27];
  P.Wp_pdp_x = (const float*)d_in[28];
  P.bp_pdp   = (const float*)d_in[29];
  P.Wp_att   = (const float*)d_in[30];
  P.bp_att   = (const float*)d_in[31];
  P.Wp_dec_f = (const float*)d_in[32];
  P.Wp_dec_x = (const float*)d_in[33];
  P.bp_dec   = (const float*)d_in[34];
  P.Wp_uatt  = (const float*)d_in[35];
  P.bp_uatt  = (const float*)d_in[36];
  P.Wp_uupd  = (const float*)d_in[37];
  P.out      = (float*)d_out;

  // 256 pixel-blocks x 2 streams = 512 blocks, 256 px per block
  gnn_fused<<<dim3(NPIX / 256, 2), dim3(256), 0, stream>>>(P);
}

// Round 11
// 66.931 us; speedup vs baseline: 1.7563x; 1.0368x over previous
//
#include <hip/hip_runtime.h>

// GNN_51539607552576 — round 11: R6 structure (best measured, 67.95 us) +
// non-temporal OUT stores (out is write-once never-read: don't let it evict
// replay-resident fea lines from L2/L3; proj's FETCH should drop).
// Phase 1 (proj): float4 pixels, 256 px/block, 4 slice-waves x 64 ch, 16-deep
//   rolling ring, LDS reduce (stride 65), 512 blocks.
// Phase 2 (gnn_node): per-output-node split (grid.y=9), nt out stores.

namespace {
constexpr int S     = 128 * 128;
constexpr int BATCH = 4;
constexpr int HID   = 10;
constexpr int INDIM = 256;
constexpr int NPIX  = BATCH * S;   // 65536

constexpr int LROW = 65;   // LDS row stride (odd -> conflict-free)
constexpr int RD   = 16;   // ring depth

struct Ptrs {
  const float* __restrict__ xp;
  const float* __restrict__ xh;
  const float* __restrict__ xf;
  const float* __restrict__ p_fea;
  const float* __restrict__ h_fea;
  const float* __restrict__ Wf_comp;  const float* __restrict__ bf_comp;
  const float* __restrict__ Wf_uatt;  const float* __restrict__ bf_uatt;
  const float* __restrict__ Wf_uupd;
  const float* __restrict__ Wh_pdp_f; const float* __restrict__ Wh_pdp_x;
  const float* __restrict__ bh_pdp;
  const float* __restrict__ Wh_att;   const float* __restrict__ bh_att;
  const float* __restrict__ Wh_cu;    const float* __restrict__ bh_cu;
  const float* __restrict__ Wh_cl;    const float* __restrict__ bh_cl;
  const float* __restrict__ Wh_dec_f; const float* __restrict__ Wh_dec_x;
  const float* __restrict__ bh_dec;
  const float* __restrict__ Wh_uatt;  const float* __restrict__ bh_uatt;
  const float* __restrict__ Wh_uupd;
  const float* __restrict__ Wp_pdp_f; const float* __restrict__ Wp_pdp_x;
  const float* __restrict__ bp_pdp;
  const float* __restrict__ Wp_att;   const float* __restrict__ bp_att;
  const float* __restrict__ Wp_dec_f; const float* __restrict__ Wp_dec_x;
  const float* __restrict__ bp_dec;
  const float* __restrict__ Wp_uatt;  const float* __restrict__ bp_uatt;
  const float* __restrict__ Wp_uupd;
  float* __restrict__ out;
  float* __restrict__ ws;
};

__device__ __forceinline__ float sigmoidf(float x) {
  return 1.0f / (1.0f + __expf(-x));
}

// ============================ Phase 1: projections ============================
// ws rows: 0..9 fh, 10..11 hdec, 12..21 fpj, 22..27 pdec. Column = pixel id.

template <int NO>  // 12 (h stream) or 16 (p stream)
__device__ __forceinline__ void proj_impl(
    float* lds,                           // [256][LROW]
    const float* __restrict__ fea,
    const float* __restrict__ Wa,         // [10][INDIM]
    const float* __restrict__ Wb,         // [NO-10][INDIM]
    float* __restrict__ ws, int obase) {
  const int t   = threadIdx.x;
  const int pxg = t & 63;
  const int sl  = __builtin_amdgcn_readfirstlane(t >> 6);  // wave-uniform slice
  const int pb  = blockIdx.x * 256;        // block pixel base
  const int b   = pb >> 14;
  const int p0  = pb & (S - 1);
  const size_t S4 = S / 4;

  float4 acc[NO];
#pragma unroll
  for (int o = 0; o < NO; ++o) acc[o] = float4{0.f, 0.f, 0.f, 0.f};

  const float4* __restrict__ base =
      (const float4*)(fea + (size_t)(b * INDIM + sl * 64) * S + p0) + pxg;

  // ---- rolling ring: RD channels in flight, consume-then-refill ----
  float4 ring[RD];
#pragma unroll
  for (int i = 0; i < RD; ++i) ring[i] = base[(size_t)i * S4];

#pragma unroll 1
  for (int cb = 0; cb < 64 - RD; cb += RD) {   // cb = 0, 16, 32
#pragma unroll
    for (int i = 0; i < RD; ++i) {
      const float4 v = ring[i];
      ring[i] = base[(size_t)(cb + RD + i) * S4];
      const int c = sl * 64 + cb + i;
#pragma unroll
      for (int o = 0; o < 10; ++o) {
        const float w = Wa[o * INDIM + c];
        acc[o].x = fmaf(v.x, w, acc[o].x);
        acc[o].y = fmaf(v.y, w, acc[o].y);
        acc[o].z = fmaf(v.z, w, acc[o].z);
        acc[o].w = fmaf(v.w, w, acc[o].w);
      }
#pragma unroll
      for (int o = 10; o < NO; ++o) {
        const float w = Wb[(o - 10) * INDIM + c];
        acc[o].x = fmaf(v.x, w, acc[o].x);
        acc[o].y = fmaf(v.y, w, acc[o].y);
        acc[o].z = fmaf(v.z, w, acc[o].z);
        acc[o].w = fmaf(v.w, w, acc[o].w);
      }
    }
  }
#pragma unroll
  for (int i = 0; i < RD; ++i) {               // epilogue: last RD channels
    const float4 v = ring[i];
    const int c = sl * 64 + (64 - RD) + i;
#pragma unroll
    for (int o = 0; o < 10; ++o) {
      const float w = Wa[o * INDIM + c];
      acc[o].x = fmaf(v.x, w, acc[o].x);
      acc[o].y = fmaf(v.y, w, acc[o].y);
      acc[o].z = fmaf(v.z, w, acc[o].z);
      acc[o].w = fmaf(v.w, w, acc[o].w);
    }
#pragma unroll
    for (int o = 10; o < NO; ++o) {
      const float w = Wb[(o - 10) * INDIM + c];
      acc[o].x = fmaf(v.x, w, acc[o].x);
      acc[o].y = fmaf(v.y, w, acc[o].y);
      acc[o].z = fmaf(v.z, w, acc[o].z);
      acc[o].w = fmaf(v.w, w, acc[o].w);
    }
  }

  // stage partials: row = sl*64 + pxg (stride-65 rows -> conflict-free)
  float* row = lds + (sl * 64 + pxg) * LROW;
#pragma unroll
  for (int o = 0; o < NO; ++o) {
    row[4 * o + 0] = acc[o].x;
    row[4 * o + 1] = acc[o].y;
    row[4 * o + 2] = acc[o].z;
    row[4 * o + 3] = acc[o].w;
  }
  __syncthreads();

  // reduce 4 slices: 256 thr = 64 pxg x 4 output-groups of K outputs
  constexpr int K = NO / 4;
  const int og = t >> 6;
#pragma unroll
  for (int k = 0; k < K; ++k) {
    const int o = og * K + k;
    float r[4] = {0.f, 0.f, 0.f, 0.f};
#pragma unroll
    for (int s2 = 0; s2 < 4; ++s2) {
      const float* rr = lds + (s2 * 64 + pxg) * LROW + 4 * o;
#pragma unroll
      for (int j = 0; j < 4; ++j) r[j] += rr[j];
    }
    float4 res; res.x = r[0]; res.y = r[1]; res.z = r[2]; res.w = r[3];
    *(float4*)(ws + (size_t)(obase + o) * NPIX + pb + pxg * 4) = res;
  }
}

__global__ __launch_bounds__(256, 2) void proj_kernel(Ptrs P) {
  __shared__ float lds[256 * LROW];   // 66.6 KB -> 2 blocks/CU
  if (blockIdx.y == 0) {
    proj_impl<12>(lds, P.h_fea, P.Wh_pdp_f, P.Wh_dec_f, P.ws, 0);
  } else {
    proj_impl<16>(lds, P.p_fea, P.Wp_pdp_f, P.Wp_dec_f, P.ws, 12);
  }
}

// ============================ Phase 2: per-node graph math ============================

__device__ __forceinline__ void att_update_store(
    const float* x, const float* m,
    const float* __restrict__ Wa, float ba, const float* __restrict__ Wu,
    float* __restrict__ outp) {
  float a = ba;
#pragma unroll
  for (int c = 0; c < HID; ++c) a = fmaf(x[c], Wa[c], a);
#pragma unroll
  for (int c = 0; c < HID; ++c) a = fmaf(m[c], Wa[HID + c], a);
  a = sigmoidf(a);
#pragma unroll
  for (int o = 0; o < HID; ++o) {
    float u = 0.f;
#pragma unroll
    for (int c = 0; c < HID; ++c) u = fmaf(x[c], Wu[o * 2 * HID + c], u);
#pragma unroll
    for (int c = 0; c < HID; ++c) u = fmaf(m[c], Wu[o * 2 * HID + HID + c], u);
    u = fmaxf(u, 0.f);
    // nt store: out is never read by the kernels -> don't pollute L2/L3
    __builtin_nontemporal_store(x[o] * (1.f - a) + u * a, outp + (size_t)o * S);
  }
}

__device__ __forceinline__ void load10(float* dst, const float* __restrict__ src,
                                       int plane, int p) {
#pragma unroll
  for (int c = 0; c < HID; ++c)
    dst[c] = src[((size_t)plane * HID + c) * S + p];
}

// grid.y = node id: 0..5 parts, 6..7 halves, 8 full
__global__ __launch_bounds__(256) void gnn_node(Ptrs P) {
  const int tid = blockIdx.x * blockDim.x + threadIdx.x;
  const int b = tid >> 14;
  const int p = tid & (S - 1);
  const int y = blockIdx.y;

  if (y == 8) {
    // ---------------- full graph ----------------
    float xh0[HID], xh1[HID], xfv[HID];
    load10(xh0, P.xh, 0 * BATCH + b, p);
    load10(xh1, P.xh, 1 * BATCH + b, p);
    load10(xfv, P.xf, b, p);
    float a0 = P.bf_comp[0], a1 = P.bf_comp[1];
#pragma unroll
    for (int c = 0; c < HID; ++c) {
      a0 = fmaf(xh0[c], P.Wf_comp[c], a0);
      a1 = fmaf(xh1[c], P.Wf_comp[HID + c], a1);
    }
    a0 = sigmoidf(a0); a1 = sigmoidf(a1);
    float msg[HID];
#pragma unroll
    for (int c = 0; c < HID; ++c) msg[c] = a0 * xh0[c] + a1 * xh1[c];
    att_update_store(xfv, msg, P.Wf_uatt, P.bf_uatt[0], P.Wf_uupd,
                     P.out + ((size_t)(8 * BATCH + b) * HID) * S + p);
  } else if (y >= 6) {
    // ---------------- half graph, node h ----------------
    const int h = y - 6;
    float xh_self[HID], xh_oth[HID], xfv[HID], fh[HID];
    load10(xh_self, P.xh, h * BATCH + b, p);
    load10(xh_oth,  P.xh, (1 - h) * BATCH + b, p);
    load10(xfv, P.xf, b, p);
#pragma unroll
    for (int o = 0; o < HID; ++o) fh[o] = P.ws[(size_t)o * NPIX + tid];
    const float hdec = P.ws[(size_t)(10 + h) * NPIX + tid];

    const int nsrc = h ? 2 : 4;
    const int sbase = h ? 4 : 0;
    const float* __restrict__ Wc = h ? P.Wh_cl : P.Wh_cu;
    const float* __restrict__ bc = h ? P.bh_cl : P.bh_cu;
    float comp[HID];
#pragma unroll
    for (int o = 0; o < HID; ++o) comp[o] = 0.f;
#pragma unroll
    for (int i = 0; i < 4; ++i) {
      if (i < nsrc) {
        float xpi[HID];
        load10(xpi, P.xp, (sbase + i) * BATCH + b, p);
        float s = bc[i];
#pragma unroll
        for (int c = 0; c < HID; ++c) s = fmaf(xpi[c], Wc[i * HID + c], s);
        s = sigmoidf(s);
#pragma unroll
        for (int c = 0; c < HID; ++c) comp[c] = fmaf(s, xpi[c], comp[c]);
      }
    }

    float a_self = P.bh_att[h], a_oth = P.bh_att[1 - h];
#pragma unroll
    for (int c = 0; c < HID; ++c) {
      a_self = fmaf(xh_self[c], P.Wh_att[h * HID + c], a_self);
      a_oth  = fmaf(xh_oth[c],  P.Wh_att[(1 - h) * HID + c], a_oth);
    }
    a_self = sigmoidf(a_self); a_oth = sigmoidf(a_oth);
    const float wg = a_oth * (1.f - a_self);

    float d = hdec + P.bh_dec[h];
#pragma unroll
    for (int c = 0; c < HID; ++c) d = fmaf(xh_self[c], P.Wh_dec_x[h * HID + c], d);
    d = sigmoidf(d);

    float m[HID];
#pragma unroll
    for (int o = 0; o < HID; ++o) {
      float dp = fh[o] + P.bh_pdp[o];
#pragma unroll
      for (int c = 0; c < HID; ++c) dp = fmaf(xh_oth[c], P.Wh_pdp_x[o * HID + c], dp);
      dp = fmaxf(dp, 0.f);
      m[o] = comp[o] + dp * wg + d * xfv[o];
    }
    att_update_store(xh_self, m, P.Wh_uatt + h * 2 * HID, P.bh_uatt[h],
                     P.Wh_uupd + h * HID * 2 * HID,
                     P.out + ((size_t)((6 + h) * BATCH + b) * HID) * S + p);
  } else {
    // ---------------- part graph, node n ----------------
    const int n = y;
    const int half = (n < 4) ? 0 : 1;
    // ADJ columns: dst0{1} dst1{0,2,3,4,5} dst2{1} dst3{1} dst4{1,5} dst5{1,4}
    const unsigned masks[6] = {0x02u, 0x3Du, 0x02u, 0x02u, 0x22u, 0x12u};
    const unsigned mask = masks[n];

    float xpn[HID], xh_s[HID], fpj[HID];
    load10(xpn, P.xp, n * BATCH + b, p);
    load10(xh_s, P.xh, half * BATCH + b, p);
#pragma unroll
    for (int o = 0; o < HID; ++o) fpj[o] = P.ws[(size_t)(12 + o) * NPIX + tid];
    const float pdecn = P.ws[(size_t)(22 + n) * NPIX + tid];

    float pattn = P.bp_att[n];
#pragma unroll
    for (int c = 0; c < HID; ++c) pattn = fmaf(xpn[c], P.Wp_att[n * HID + c], pattn);
    pattn = sigmoidf(pattn);

    float msum[HID];
#pragma unroll
    for (int o = 0; o < HID; ++o) msum[o] = 0.f;
#pragma unroll
    for (int src = 0; src < 6; ++src) {
      if (mask & (1u << src)) {
        float xps[HID];
        load10(xps, P.xp, src * BATCH + b, p);
        float ps = P.bp_att[src];
#pragma unroll
        for (int c = 0; c < HID; ++c) ps = fmaf(xps[c], P.Wp_att[src * HID + c], ps);
        ps = sigmoidf(ps);
#pragma unroll
        for (int o = 0; o < HID; ++o) {
          float dp = fpj[o] + P.bp_pdp[o];
#pragma unroll
          for (int c = 0; c < HID; ++c) dp = fmaf(xps[c], P.Wp_pdp_x[o * HID + c], dp);
          msum[o] = fmaf(fmaxf(dp, 0.f), ps, msum[o]);
        }
      }
    }

    float dg = pdecn + P.bp_dec[n];
#pragma unroll
    for (int c = 0; c < HID; ++c) dg = fmaf(xpn[c], P.Wp_dec_x[n * HID + c], dg);
    dg = sigmoidf(dg);

    const float onem = 1.f - pattn;
    float m[HID];
#pragma unroll
    for (int o = 0; o < HID; ++o) m[o] = onem * msum[o] + dg * xh_s[o];

    att_update_store(xpn, m, P.Wp_uatt + n * 2 * HID, P.bp_uatt[n],
                     P.Wp_uupd + n * HID * 2 * HID,
                     P.out + ((size_t)(n * BATCH + b) * HID) * S + p);
  }
}

}  // namespace

extern "C" void kernel_launch(void* const* d_in, const int* in_sizes, int n_in,
                              void* d_out, int out_size, void* d_ws, size_t ws_size,
                              hipStream_t stream) {
  Ptrs P;
  P.xp       = (const float*)d_in[0];
  P.xh       = (const float*)d_in[1];
  P.xf       = (const float*)d_in[2];
  // d_in[3] = bg_node (unused)
  P.p_fea    = (const float*)d_in[4];
  P.h_fea    = (const float*)d_in[5];
  // d_in[6] = f_fea (unused)
  P.Wf_comp  = (const float*)d_in[7];
  P.bf_comp  = (const float*)d_in[8];
  P.Wf_uatt  = (const float*)d_in[9];
  P.bf_uatt  = (const float*)d_in[10];
  P.Wf_uupd  = (const float*)d_in[11];
  P.Wh_pdp_f = (const float*)d_in[12];
  P.Wh_pdp_x = (const float*)d_in[13];
  P.bh_pdp   = (const float*)d_in[14];
  P.Wh_att   = (const float*)d_in[15];
  P.bh_att   = (const float*)d_in[16];
  P.Wh_cu    = (const float*)d_in[17];
  P.bh_cu    = (const float*)d_in[18];
  P.Wh_cl    = (const float*)d_in[19];
  P.bh_cl    = (const float*)d_in[20];
  P.Wh_dec_f = (const float*)d_in[21];
  P.Wh_dec_x = (const float*)d_in[22];
  P.bh_dec   = (const float*)d_in[23];
  P.Wh_uatt  = (const float*)d_in[24];
  P.bh_uatt  = (const float*)d_in[25];
  P.Wh_uupd  = (const float*)d_in[26];
  P.Wp_pdp_f = (const float*)d_in[27];
  P.Wp_pdp_x = (const float*)d_in[28];
  P.bp_pdp   = (const float*)d_in[29];
  P.Wp_att   = (const float*)d_in[30];
  P.bp_att   = (const float*)d_in[31];
  P.Wp_dec_f = (const float*)d_in[32];
  P.Wp_dec_x = (const float*)d_in[33];
  P.bp_dec   = (const float*)d_in[34];
  P.Wp_uatt  = (const float*)d_in[35];
  P.bp_uatt  = (const float*)d_in[36];
  P.Wp_uupd  = (const float*)d_in[37];
  P.out      = (float*)d_out;
  P.ws       = (float*)d_ws;   // 28 * 65536 * 4 = 7.34 MB

  // Phase 1: 256 pixel-blocks x 2 streams = 512 blocks, 256 px per block
  proj_kernel<<<dim3(NPIX / 256, 2), dim3(256), 0, stream>>>(P);
  // Phase 2: 256 pixel-blocks x 9 output nodes
  gnn_node<<<dim3(NPIX / 256, 9), dim3(256), 0, stream>>>(P);
}